// Round 3
// baseline (369.583 us; speedup 1.0000x reference)
//
#include <hip/hip_runtime.h>
#include <math.h>

#define NSPECIES 7
#define NRBF 16
#define NPAIRS_SP 28   // 7*8/2
#define SUBLEN 32      // 8*4
#define ROWLEN 1008    // NSPECIES*NRBF + NPAIRS_SP*SUBLEN = 112 + 896
#define ANG_OFF 112
#define RAD_CAP 32     // max neighbors per atom = M-1 = 23 < 32
#define ANG_CAP 256    // max triples per central atom = C(23,2) = 253 < 256

// ---- binning: pairs -> per-atom radial lists, triples -> per-central-atom lists ----

__global__ void bin_pairs(const int* __restrict__ pair_indices,
                          int* __restrict__ rad_cnt, int* __restrict__ rad_list,
                          int P) {
    int p = blockIdx.x * blockDim.x + threadIdx.x;
    if (p >= P) return;
    int i = pair_indices[p];
    int j = pair_indices[P + p];
    int si = atomicAdd(&rad_cnt[i], 1);
    if (si < RAD_CAP) rad_list[i * RAD_CAP + si] = (p << 1);       // side 0: I am i, other is j
    int sj = atomicAdd(&rad_cnt[j], 1);
    if (sj < RAD_CAP) rad_list[j * RAD_CAP + sj] = (p << 1) | 1;   // side 1: I am j, other is i
}

__global__ void bin_triples(const int* __restrict__ central_atom_index,
                            int* __restrict__ ang_cnt, int* __restrict__ ang_list,
                            int T) {
    int t = blockIdx.x * blockDim.x + threadIdx.x;
    if (t >= T) return;
    int ca = central_atom_index[t];
    int s = atomicAdd(&ang_cnt[ca], 1);
    if (s < ANG_CAP) ang_list[ca * ANG_CAP + s] = t;
}

// ---- gather: one wave per atom, accumulate row in LDS, write once ----

__global__ __launch_bounds__(256) void aev_kernel(
        const float* __restrict__ d_ij,
        const float* __restrict__ r_ij,
        const int* __restrict__ pair_indices,
        const int* __restrict__ species,
        const int* __restrict__ close_idx,
        const int* __restrict__ pair_index12,
        const int* __restrict__ sign12,
        const int* __restrict__ rad_cnt, const int* __restrict__ rad_list,
        const int* __restrict__ ang_cnt, const int* __restrict__ ang_list,
        float* __restrict__ out,
        int P, int T, int natoms) {
    __shared__ float rows[4][ROWLEN];

    int w = threadIdx.x >> 6;      // wave in block
    int lane = threadIdx.x & 63;
    int a = blockIdx.x * 4 + w;    // atom
    bool live = (a < natoms);

    float* row = rows[w];
    // zero this wave's row
    for (int c = lane; c < ROWLEN; c += 64) row[c] = 0.0f;
    __syncthreads();

    if (live) {
        // ---- radial ----
        int cnt = min(rad_cnt[a], RAD_CAP);
        int n16 = cnt * NRBF;
        for (int idx = lane; idx < n16; idx += 64) {
            int s = idx >> 4;
            int k = idx & 15;
            int code = rad_list[a * RAD_CAP + s];
            int p = code >> 1;
            int side = code & 1;
            float d = d_ij[p];
            int other = pair_indices[(side ? 0 : P) + p];
            int sp = species[other];
            float fc = (d <= 0.51f) ? 0.5f * (cosf(d * (float)(M_PI / 0.51)) + 1.0f) : 0.0f;
            float shfr = 0.08f + (float)k * 0.026875f;
            float diff = d - shfr;
            float rfv = 0.25f * expf(-1970.0f * diff * diff) * fc;
            atomicAdd(&row[sp * NRBF + k], rfv);
        }

        // ---- angular ----
        int acnt = min(ang_cnt[a], ANG_CAP);
        int n32 = acnt * SUBLEN;
        for (int idx = lane; idx < n32; idx += 64) {
            int s = idx >> 5;
            int l = idx & 31;
            int t = ang_list[a * ANG_CAP + s];

            int p1 = pair_index12[t];
            int p2 = pair_index12[T + t];
            int s1 = sign12[t];
            int s2 = sign12[T + t];
            int gp1 = close_idx[p1];
            int gp2 = close_idx[p2];

            float sg1 = (float)s1, sg2 = (float)s2;
            float v1x = r_ij[gp1 * 3 + 0] * sg1;
            float v1y = r_ij[gp1 * 3 + 1] * sg1;
            float v1z = r_ij[gp1 * 3 + 2] * sg1;
            float v2x = r_ij[gp2 * 3 + 0] * sg2;
            float v2y = r_ij[gp2 * 3 + 1] * sg2;
            float v2z = r_ij[gp2 * 3 + 2] * sg2;

            int spa = species[pair_indices[(s1 == 1 ? P : 0) + gp1]];
            int spb = species[pair_indices[(s2 == 1 ? P : 0) + gp2]];

            float d1 = sqrtf(v1x * v1x + v1y * v1y + v1z * v1z);
            float d2 = sqrtf(v2x * v2x + v2y * v2y + v2z * v2z);
            float dot = v1x * v2x + v1y * v2y + v1z * v2z;

            float cosang = 0.95f * dot / (d1 * d2);
            float sinang = sqrtf(fmaxf(1.0f - cosang * cosang, 0.0f));

            float fc1 = (d1 <= 0.35f) ? 0.5f * (cosf(d1 * (float)(M_PI / 0.35)) + 1.0f) : 0.0f;
            float fc2 = (d2 <= 0.35f) ? 0.5f * (cosf(d2 * (float)(M_PI / 0.35)) + 1.0f) : 0.0f;
            float fcj = fc1 * fc2;

            int aa = l >> 2;
            int z = l & 3;
            float shfa = 0.08f + (float)aa * 0.03375f;
            float dm = (d1 + d2) * 0.5f - shfa;
            float f2 = expf(-800.0f * dm * dm);

            const float c8 = 0.92387953251f;   // cos(pi/8)
            const float s8 = 0.38268343236f;   // sin(pi/8)
            bool mid = (z == 1) | (z == 2);
            float cmag = mid ? s8 : c8;
            float smag = mid ? c8 : s8;
            float cz = (z >= 2) ? -cmag : cmag;

            float base = 0.5f * (1.0f + cosang * cz + sinang * smag);
            float x = base * base;  // ^2
            x = x * x;              // ^4
            x = x * x;              // ^8
            x = x * x;              // ^16
            x = x * x;              // ^32

            float term = 2.0f * f2 * x * fcj;

            int lo = min(spa, spb), hi = max(spa, spb);
            int triu = lo * NSPECIES - (lo * (lo - 1)) / 2 + (hi - lo);

            atomicAdd(&row[ANG_OFF + triu * SUBLEN + l], term);
        }
    }

    __syncthreads();

    if (live) {
        // write full row once, coalesced float4 (ROWLEN=1008 = 252 float4)
        float4* dst = (float4*)(out + (size_t)a * ROWLEN);
        const float4* src = (const float4*)row;
        for (int c = lane; c < ROWLEN / 4; c += 64) {
            dst[c] = src[c];
        }
    }
}

extern "C" void kernel_launch(void* const* d_in, const int* in_sizes, int n_in,
                              void* d_out, int out_size, void* d_ws, size_t ws_size,
                              hipStream_t stream) {
    const float* d_ij               = (const float*)d_in[0];
    const float* r_ij               = (const float*)d_in[1];
    const int*   pair_indices       = (const int*)d_in[2];
    const int*   species            = (const int*)d_in[3];
    const int*   close_idx          = (const int*)d_in[4];
    const int*   central_atom_index = (const int*)d_in[5];
    const int*   pair_index12       = (const int*)d_in[6];
    const int*   sign12             = (const int*)d_in[7];
    float* out = (float*)d_out;

    int P      = in_sizes[0];   // pairs
    int T      = in_sizes[5];   // angular triples
    int natoms = in_sizes[3];   // 96000

    // workspace layout
    int*  rad_cnt  = (int*)d_ws;
    int*  ang_cnt  = rad_cnt + natoms;
    int*  rad_list = ang_cnt + natoms;
    int*  ang_list = rad_list + (size_t)natoms * RAD_CAP;
    // total: natoms*(2 + 32 + 256) * 4B ~= 111.4 MB

    // zero the counters (768 KB) — must be done every call
    hipMemsetAsync(rad_cnt, 0, (size_t)natoms * 2 * sizeof(int), stream);

    bin_pairs<<<(P + 255) / 256, 256, 0, stream>>>(pair_indices, rad_cnt, rad_list, P);
    bin_triples<<<(T + 255) / 256, 256, 0, stream>>>(central_atom_index, ang_cnt, ang_list, T);

    int blocks = (natoms + 3) / 4;   // 4 atoms (waves) per block
    aev_kernel<<<blocks, 256, 0, stream>>>(d_ij, r_ij, pair_indices, species, close_idx,
                                           pair_index12, sign12,
                                           rad_cnt, rad_list, ang_cnt, ang_list,
                                           out, P, T, natoms);
}

// Round 5
// 306.061 us; speedup vs baseline: 1.2075x; 1.2075x over previous
//
#include <hip/hip_runtime.h>
#include <math.h>

#define NSPECIES 7
#define NRBF 16
#define NPAIRS_SP 28     // 7*8/2
#define SUBLEN 32        // 8*4
#define ROWLEN 1008      // 7*16 + 28*32 = 112 + 896
#define ANG_OFF 112
#define M_ATOMS 24       // atoms per molecule
#define APB 12           // atoms (rows) per block = half molecule
#define THREADS 512

typedef float v4f __attribute__((ext_vector_type(4)));   // clang vector: valid for nontemporal builtins

// One block per 12 atoms (half-molecule). Exploits sortedness:
//  - pair_indices[0] is non-decreasing (molecule-major order)
//  - central_atom_index is non-decreasing (np.repeat of sorted uniq)
// Per-block work ranges via binary search: no binning, no scratch, no global
// atomics, no pre-zero. Rows accumulate in LDS; one contiguous 48KB
// nontemporal write per block.
__global__ __launch_bounds__(THREADS) void aev_mol_kernel(
        const float* __restrict__ d_ij,
        const float* __restrict__ r_ij,
        const int* __restrict__ pair_indices,
        const int* __restrict__ species,
        const int* __restrict__ close_idx,
        const int* __restrict__ central_atom_index,
        const int* __restrict__ pair_index12,
        const int* __restrict__ sign12,
        float* __restrict__ out,
        int P, int T, int natoms) {
    __shared__ float rows[APB * ROWLEN];   // 48384 B

    int tid = threadIdx.x;
    int base = blockIdx.x * APB;                 // first atom row owned by this block
    if (base >= natoms) return;
    int molbase = (base / M_ATOMS) * M_ATOMS;    // molecule start atom

    // zero LDS rows
    for (int c = tid; c < APB * ROWLEN; c += THREADS) rows[c] = 0.0f;

    // ---- uniform binary searches (all threads redundant; broadcast loads) ----
    int p_lo, p_hi, t_lo, t_hi;
    {
        int lo = 0, hi = P;
        while (lo < hi) { int mid = (lo + hi) >> 1; if (pair_indices[mid] < molbase) lo = mid + 1; else hi = mid; }
        p_lo = lo; hi = P;
        while (lo < hi) { int mid = (lo + hi) >> 1; if (pair_indices[mid] < molbase + M_ATOMS) lo = mid + 1; else hi = mid; }
        p_hi = lo;
    }
    {
        int lo = 0, hi = T;
        while (lo < hi) { int mid = (lo + hi) >> 1; if (central_atom_index[mid] < base) lo = mid + 1; else hi = mid; }
        t_lo = lo; hi = T;
        while (lo < hi) { int mid = (lo + hi) >> 1; if (central_atom_index[mid] < base + APB) lo = mid + 1; else hi = mid; }
        t_hi = lo;
    }

    __syncthreads();

    // ---- radial: all pairs of the molecule; keep rows in [base, base+APB) ----
    int npair = p_hi - p_lo;
    for (int idx = tid; idx < npair * NRBF; idx += THREADS) {
        int p = p_lo + (idx >> 4);
        int k = idx & 15;
        float d = d_ij[p];
        int i = pair_indices[p];
        int j = pair_indices[P + p];
        int si = species[i];
        int sj = species[j];
        float fc = (d <= 0.51f) ? 0.5f * (cosf(d * (float)(M_PI / 0.51)) + 1.0f) : 0.0f;
        float shfr = 0.08f + (float)k * 0.026875f;
        float diff = d - shfr;
        float rfv = 0.25f * expf(-1970.0f * diff * diff) * fc;
        int li = i - base;
        int lj = j - base;
        if ((unsigned)li < APB) atomicAdd(&rows[li * ROWLEN + sj * NRBF + k], rfv);
        if ((unsigned)lj < APB) atomicAdd(&rows[lj * ROWLEN + si * NRBF + k], rfv);
    }

    // ---- angular: triples whose central atom is in [base, base+APB) ----
    int ntrip = t_hi - t_lo;
    for (int idx = tid; idx < ntrip * SUBLEN; idx += THREADS) {
        int t = t_lo + (idx >> 5);
        int l = idx & 31;

        int p1 = pair_index12[t];
        int p2 = pair_index12[T + t];
        int s1 = sign12[t];
        int s2 = sign12[T + t];
        int ca = central_atom_index[t];
        int gp1 = close_idx[p1];
        int gp2 = close_idx[p2];

        float sg1 = (float)s1, sg2 = (float)s2;
        float v1x = r_ij[gp1 * 3 + 0] * sg1;
        float v1y = r_ij[gp1 * 3 + 1] * sg1;
        float v1z = r_ij[gp1 * 3 + 2] * sg1;
        float v2x = r_ij[gp2 * 3 + 0] * sg2;
        float v2y = r_ij[gp2 * 3 + 1] * sg2;
        float v2z = r_ij[gp2 * 3 + 2] * sg2;

        int spa = species[pair_indices[(s1 == 1 ? P : 0) + gp1]];
        int spb = species[pair_indices[(s2 == 1 ? P : 0) + gp2]];

        float d1 = sqrtf(v1x * v1x + v1y * v1y + v1z * v1z);
        float d2 = sqrtf(v2x * v2x + v2y * v2y + v2z * v2z);
        float dot = v1x * v2x + v1y * v2y + v1z * v2z;

        float cosang = 0.95f * dot / (d1 * d2);
        float sinang = sqrtf(fmaxf(1.0f - cosang * cosang, 0.0f));  // ang in [0,pi]

        float fc1 = (d1 <= 0.35f) ? 0.5f * (cosf(d1 * (float)(M_PI / 0.35)) + 1.0f) : 0.0f;
        float fc2 = (d2 <= 0.35f) ? 0.5f * (cosf(d2 * (float)(M_PI / 0.35)) + 1.0f) : 0.0f;
        float fcj = fc1 * fc2;

        int aa = l >> 2;
        int z = l & 3;
        float shfa = 0.08f + (float)aa * 0.03375f;
        float dm = (d1 + d2) * 0.5f - shfa;
        float f2 = expf(-800.0f * dm * dm);

        // cos(ang - SHFZ[z]) = cosang*cos(SHFZ) + sinang*sin(SHFZ)
        // SHFZ = pi/8 + z*pi/4: cos = {c8, s8, -s8, -c8}, sin = {s8, c8, c8, s8}
        const float c8 = 0.92387953251f;
        const float s8 = 0.38268343236f;
        bool mid = (z == 1) | (z == 2);
        float cmag = mid ? s8 : c8;
        float smag = mid ? c8 : s8;
        float cz = (z >= 2) ? -cmag : cmag;

        float bse = 0.5f * (1.0f + cosang * cz + sinang * smag);
        float x = bse * bse;  // ^2
        x = x * x;            // ^4
        x = x * x;            // ^8
        x = x * x;            // ^16
        x = x * x;            // ^32

        float term = 2.0f * f2 * x * fcj;

        int lo = min(spa, spb), hi = max(spa, spb);
        int triu = lo * NSPECIES - (lo * (lo - 1)) / 2 + (hi - lo);

        atomicAdd(&rows[(ca - base) * ROWLEN + ANG_OFF + triu * SUBLEN + l], term);
    }

    __syncthreads();

    // ---- write 12 rows = 48384 contiguous bytes, nontemporal v4f ----
    int nrows = min(APB, natoms - base);
    v4f* dst = (v4f*)(out + (size_t)base * ROWLEN);
    const v4f* src = (const v4f*)rows;
    int n4 = nrows * (ROWLEN / 4);   // 3024 for full block
    for (int c = tid; c < n4; c += THREADS) {
        v4f v = src[c];
        __builtin_nontemporal_store(v, &dst[c]);
    }
}

extern "C" void kernel_launch(void* const* d_in, const int* in_sizes, int n_in,
                              void* d_out, int out_size, void* d_ws, size_t ws_size,
                              hipStream_t stream) {
    const float* d_ij               = (const float*)d_in[0];
    const float* r_ij               = (const float*)d_in[1];
    const int*   pair_indices       = (const int*)d_in[2];
    const int*   species            = (const int*)d_in[3];
    const int*   close_idx          = (const int*)d_in[4];
    const int*   central_atom_index = (const int*)d_in[5];
    const int*   pair_index12       = (const int*)d_in[6];
    const int*   sign12             = (const int*)d_in[7];
    float* out = (float*)d_out;

    int P      = in_sizes[0];   // pairs
    int T      = in_sizes[5];   // angular triples
    int natoms = in_sizes[3];   // 96000

    int blocks = (natoms + APB - 1) / APB;   // 8000
    aev_mol_kernel<<<blocks, THREADS, 0, stream>>>(d_ij, r_ij, pair_indices, species,
                                                   close_idx, central_atom_index,
                                                   pair_index12, sign12,
                                                   out, P, T, natoms);
}

// Round 6
// 217.864 us; speedup vs baseline: 1.6964x; 1.4048x over previous
//
#include <hip/hip_runtime.h>
#include <math.h>

#define NSPECIES 7
#define NRBF 16
#define NPAIRS_SP 28     // 7*8/2
#define SUBLEN 32        // 8*4
#define ROWLEN 1008      // 7*16 + 28*32 = 112 + 896
#define ANG_OFF 112
#define M_ATOMS 24       // atoms per molecule
#define APB 12           // atoms (rows) per block = half molecule
#define THREADS 512

typedef float v4f __attribute__((ext_vector_type(4)));

// ---------------- k1: per-pair precompute + molecule start table ----------------
// rec: p_val = 0.25*fc(d), p_d = d, p_di = (i<<3)|sj, p_dj = (j<<3)|si
__global__ void pair_pre(const float* __restrict__ d_ij,
                         const int* __restrict__ pair_indices,
                         const int* __restrict__ species,
                         float* __restrict__ p_val, float* __restrict__ p_d,
                         int* __restrict__ p_di, int* __restrict__ p_dj,
                         int* __restrict__ pstart,
                         int P, int nmol) {
    int p = blockIdx.x * blockDim.x + threadIdx.x;
    if (p > P) return;

    if (p < P) {
        float d = d_ij[p];
        int i = pair_indices[p];
        int j = pair_indices[P + p];
        int si = species[i];
        int sj = species[j];
        float fc = (d <= 0.51f) ? 0.5f * (__cosf(d * (float)(M_PI / 0.51)) + 1.0f) : 0.0f;
        p_val[p] = 0.25f * fc;
        p_d[p]   = d;
        p_di[p]  = (i << 3) | sj;
        p_dj[p]  = (j << 3) | si;
    }

    // boundary fill for pstart[0..nmol]
    int m     = (p < P) ? pair_indices[p] / M_ATOMS : nmol;
    int mprev = (p > 0) ? pair_indices[p - 1] / M_ATOMS : -1;
    for (int v = mprev + 1; v <= m; ++v) pstart[v] = p;
}

// ---------------- k2: per-triple precompute + block start table ----------------
// rec: t_hs = (d1+d2)/2, t_fcj2 = 2*fc1*fc2, t_cos, t_sin, t_dst = (ca<<5)|triu
__global__ void trip_pre(const float* __restrict__ r_ij,
                         const int* __restrict__ pair_indices,
                         const int* __restrict__ species,
                         const int* __restrict__ close_idx,
                         const int* __restrict__ central_atom_index,
                         const int* __restrict__ pair_index12,
                         const int* __restrict__ sign12,
                         float* __restrict__ t_hs, float* __restrict__ t_fcj2,
                         float* __restrict__ t_cos, float* __restrict__ t_sin,
                         int* __restrict__ t_dst,
                         int* __restrict__ tstart,
                         int P, int T, int nblk) {
    int t = blockIdx.x * blockDim.x + threadIdx.x;
    if (t > T) return;

    if (t < T) {
        int p1 = pair_index12[t];
        int p2 = pair_index12[T + t];
        int s1 = sign12[t];
        int s2 = sign12[T + t];
        int ca = central_atom_index[t];
        int gp1 = close_idx[p1];
        int gp2 = close_idx[p2];

        float sg1 = (float)s1, sg2 = (float)s2;
        float v1x = r_ij[gp1 * 3 + 0] * sg1;
        float v1y = r_ij[gp1 * 3 + 1] * sg1;
        float v1z = r_ij[gp1 * 3 + 2] * sg1;
        float v2x = r_ij[gp2 * 3 + 0] * sg2;
        float v2y = r_ij[gp2 * 3 + 1] * sg2;
        float v2z = r_ij[gp2 * 3 + 2] * sg2;

        int spa = species[pair_indices[(s1 == 1 ? P : 0) + gp1]];
        int spb = species[pair_indices[(s2 == 1 ? P : 0) + gp2]];

        float d1 = sqrtf(v1x * v1x + v1y * v1y + v1z * v1z);
        float d2 = sqrtf(v2x * v2x + v2y * v2y + v2z * v2z);
        float dot = v1x * v2x + v1y * v2y + v1z * v2z;

        float cosang = 0.95f * dot / (d1 * d2);
        float sinang = sqrtf(fmaxf(1.0f - cosang * cosang, 0.0f));

        float fc1 = (d1 <= 0.35f) ? 0.5f * (__cosf(d1 * (float)(M_PI / 0.35)) + 1.0f) : 0.0f;
        float fc2 = (d2 <= 0.35f) ? 0.5f * (__cosf(d2 * (float)(M_PI / 0.35)) + 1.0f) : 0.0f;

        int lo = min(spa, spb), hi = max(spa, spb);
        int triu = lo * NSPECIES - (lo * (lo - 1)) / 2 + (hi - lo);

        t_hs[t]   = (d1 + d2) * 0.5f;
        t_fcj2[t] = 2.0f * fc1 * fc2;
        t_cos[t]  = cosang;
        t_sin[t]  = sinang;
        t_dst[t]  = (ca << 5) | triu;
    }

    // boundary fill for tstart[0..nblk] (blocks of APB atoms)
    int b     = (t < T) ? central_atom_index[t] / APB : nblk;
    int bprev = (t > 0) ? central_atom_index[t - 1] / APB : -1;
    for (int v = bprev + 1; v <= b; ++v) tstart[v] = t;
}

// ---------------- k3: per-block accumulate in LDS, one contiguous nt write ----------------
__global__ __launch_bounds__(THREADS) void aev_main(
        const float* __restrict__ p_val, const float* __restrict__ p_d,
        const int* __restrict__ p_di, const int* __restrict__ p_dj,
        const float* __restrict__ t_hs, const float* __restrict__ t_fcj2,
        const float* __restrict__ t_cos, const float* __restrict__ t_sin,
        const int* __restrict__ t_dst,
        const int* __restrict__ pstart, const int* __restrict__ tstart,
        float* __restrict__ out, int natoms) {
    __shared__ float rows[APB * ROWLEN];   // 48384 B

    int tid = threadIdx.x;
    int blk = blockIdx.x;
    int base = blk * APB;
    if (base >= natoms) return;
    int mol = blk >> 1;                    // molecule (24 atoms) = 2 blocks

    // zero LDS rows (v4f)
    {
        v4f z = {0.f, 0.f, 0.f, 0.f};
        v4f* r4 = (v4f*)rows;
        for (int c = tid; c < APB * ROWLEN / 4; c += THREADS) r4[c] = z;
    }

    int p_lo = pstart[mol];
    int p_hi = pstart[mol + 1];
    int t_lo = tstart[blk];
    int t_hi = tstart[blk + 1];

    __syncthreads();

    // ---- radial: molecule's pairs; keep rows inside [base, base+APB) ----
    int nrad = (p_hi - p_lo) * NRBF;
    for (int idx = tid; idx < nrad; idx += THREADS) {
        int p = p_lo + (idx >> 4);
        int k = idx & 15;
        float val = p_val[p];
        float d   = p_d[p];
        int di = p_di[p];
        int dj = p_dj[p];
        float shfr = 0.08f + (float)k * 0.026875f;
        float diff = d - shfr;
        float rfv = val * __expf(-1970.0f * diff * diff);
        int li = (di >> 3) - base;
        int lj = (dj >> 3) - base;
        if ((unsigned)li < APB) atomicAdd(&rows[li * ROWLEN + (di & 7) * NRBF + k], rfv);
        if ((unsigned)lj < APB) atomicAdd(&rows[lj * ROWLEN + (dj & 7) * NRBF + k], rfv);
    }

    // ---- angular: this block's triples (partitioned by central atom / APB) ----
    int nang = (t_hi - t_lo) * SUBLEN;
    for (int idx = tid; idx < nang; idx += THREADS) {
        int t = t_lo + (idx >> 5);
        int l = idx & 31;

        float hs   = t_hs[t];
        float fcj2 = t_fcj2[t];
        float ca_c = t_cos[t];
        float ca_s = t_sin[t];
        int dst    = t_dst[t];

        int aa = l >> 2;
        int z = l & 3;

        float shfa = 0.08f + (float)aa * 0.03375f;
        float dm = hs - shfa;
        float f2 = __expf(-800.0f * dm * dm);

        // cos(ang - SHFZ[z]) = cosang*cos(SHFZ) + sinang*sin(SHFZ)
        const float c8 = 0.92387953251f;   // cos(pi/8)
        const float s8 = 0.38268343236f;   // sin(pi/8)
        bool midz = (z == 1) | (z == 2);
        float cmag = midz ? s8 : c8;
        float smag = midz ? c8 : s8;
        float cz = (z >= 2) ? -cmag : cmag;

        float bse = 0.5f * (1.0f + ca_c * cz + ca_s * smag);
        float x = bse * bse;  // ^2
        x = x * x;            // ^4
        x = x * x;            // ^8
        x = x * x;            // ^16
        x = x * x;            // ^32

        float term = fcj2 * f2 * x;

        int row = (dst >> 5) - base;          // guaranteed in [0, APB)
        int triu = dst & 31;
        atomicAdd(&rows[row * ROWLEN + ANG_OFF + triu * SUBLEN + l], term);
    }

    __syncthreads();

    // ---- write 12 rows = 48384 contiguous bytes, nontemporal v4f ----
    int nrows = min(APB, natoms - base);
    v4f* dstp = (v4f*)(out + (size_t)base * ROWLEN);
    const v4f* src = (const v4f*)rows;
    int n4 = nrows * (ROWLEN / 4);
    for (int c = tid; c < n4; c += THREADS) {
        v4f v = src[c];
        __builtin_nontemporal_store(v, &dstp[c]);
    }
}

extern "C" void kernel_launch(void* const* d_in, const int* in_sizes, int n_in,
                              void* d_out, int out_size, void* d_ws, size_t ws_size,
                              hipStream_t stream) {
    const float* d_ij               = (const float*)d_in[0];
    const float* r_ij               = (const float*)d_in[1];
    const int*   pair_indices       = (const int*)d_in[2];
    const int*   species            = (const int*)d_in[3];
    const int*   close_idx          = (const int*)d_in[4];
    const int*   central_atom_index = (const int*)d_in[5];
    const int*   pair_index12       = (const int*)d_in[6];
    const int*   sign12             = (const int*)d_in[7];
    float* out = (float*)d_out;

    int P      = in_sizes[0];   // pairs
    int T      = in_sizes[5];   // angular triples
    int natoms = in_sizes[3];   // 96000
    int nmol   = natoms / M_ATOMS;   // 4000
    int nblk   = natoms / APB;       // 8000

    // workspace layout (all 4-byte aligned)
    char* w = (char*)d_ws;
    float* p_val = (float*)w;              w += (size_t)P * 4;
    float* p_d   = (float*)w;              w += (size_t)P * 4;
    int*   p_di  = (int*)w;                w += (size_t)P * 4;
    int*   p_dj  = (int*)w;                w += (size_t)P * 4;
    float* t_hs_   = (float*)w;            w += (size_t)T * 4;
    float* t_fcj2_ = (float*)w;            w += (size_t)T * 4;
    float* t_cos_  = (float*)w;            w += (size_t)T * 4;
    float* t_sin_  = (float*)w;            w += (size_t)T * 4;
    int*   t_dst_  = (int*)w;              w += (size_t)T * 4;
    int*   pstart  = (int*)w;              w += (size_t)(nmol + 1) * 4;
    int*   tstart  = (int*)w;

    pair_pre<<<(P + 256) / 256, 256, 0, stream>>>(d_ij, pair_indices, species,
                                                  p_val, p_d, p_di, p_dj, pstart, P, nmol);
    trip_pre<<<(T + 256) / 256, 256, 0, stream>>>(r_ij, pair_indices, species, close_idx,
                                                  central_atom_index, pair_index12, sign12,
                                                  t_hs_, t_fcj2_, t_cos_, t_sin_, t_dst_,
                                                  tstart, P, T, nblk);
    aev_main<<<nblk, THREADS, 0, stream>>>(p_val, p_d, p_di, p_dj,
                                           t_hs_, t_fcj2_, t_cos_, t_sin_, t_dst_,
                                           pstart, tstart, out, natoms);
}

// Round 7
// 215.029 us; speedup vs baseline: 1.7188x; 1.0132x over previous
//
#include <hip/hip_runtime.h>
#include <math.h>

#define NSPECIES 7
#define NRBF 16
#define SUBLEN 32
#define ROWLEN 1008      // 112 + 896
#define ANG_OFF 112
#define RADLEN 112
#define ANGLEN 896
#define M_ATOMS 24
#define APC 8            // atoms per block, angular kernel
#define MAXPAIR 276      // C(24,2)

typedef float v4f __attribute__((ext_vector_type(4)));

// ---------------- kA: triple records + boundary tables ----------------
// t_rec = {halfsum, 2*fc1*fc2, cosang, sinang}; t_dst = (ca<<5)|triu
// pstart[mol] / tstart[8-atom group] boundary tables from sorted inputs.
__global__ void setup_kernel(const float* __restrict__ r_ij,
                             const int* __restrict__ pair_indices,
                             const int* __restrict__ species,
                             const int* __restrict__ close_idx,
                             const int* __restrict__ central_atom_index,
                             const int* __restrict__ pair_index12,
                             const int* __restrict__ sign12,
                             v4f* __restrict__ t_rec, int* __restrict__ t_dst,
                             int* __restrict__ pstart, int* __restrict__ tstart,
                             int P, int T, int nmol, int ngrp) {
    int t = blockIdx.x * blockDim.x + threadIdx.x;

    if (t <= P) {
        int m  = (t < P) ? pair_indices[t] / M_ATOMS : nmol;
        int mp = (t > 0) ? pair_indices[t - 1] / M_ATOMS : -1;
        for (int v = mp + 1; v <= m; ++v) pstart[v] = t;
    }
    if (t <= T) {
        int g  = (t < T) ? (central_atom_index[t] >> 3) : ngrp;
        int gp = (t > 0) ? (central_atom_index[t - 1] >> 3) : -1;
        for (int v = gp + 1; v <= g; ++v) tstart[v] = t;
    }
    if (t < T) {
        int p1 = pair_index12[t];
        int p2 = pair_index12[T + t];
        int s1 = sign12[t];
        int s2 = sign12[T + t];
        int ca = central_atom_index[t];
        int gp1 = close_idx[p1];
        int gp2 = close_idx[p2];

        float sg1 = (float)s1, sg2 = (float)s2;
        float v1x = r_ij[gp1 * 3 + 0] * sg1;
        float v1y = r_ij[gp1 * 3 + 1] * sg1;
        float v1z = r_ij[gp1 * 3 + 2] * sg1;
        float v2x = r_ij[gp2 * 3 + 0] * sg2;
        float v2y = r_ij[gp2 * 3 + 1] * sg2;
        float v2z = r_ij[gp2 * 3 + 2] * sg2;

        int spa = species[pair_indices[(s1 == 1 ? P : 0) + gp1]];
        int spb = species[pair_indices[(s2 == 1 ? P : 0) + gp2]];

        float d1 = sqrtf(v1x * v1x + v1y * v1y + v1z * v1z);
        float d2 = sqrtf(v2x * v2x + v2y * v2y + v2z * v2z);
        float dot = v1x * v2x + v1y * v2y + v1z * v2z;

        float cosang = 0.95f * dot / (d1 * d2);
        float sinang = sqrtf(fmaxf(1.0f - cosang * cosang, 0.0f));

        float fc1 = (d1 <= 0.35f) ? 0.5f * (__cosf(d1 * (float)(M_PI / 0.35)) + 1.0f) : 0.0f;
        float fc2 = (d2 <= 0.35f) ? 0.5f * (__cosf(d2 * (float)(M_PI / 0.35)) + 1.0f) : 0.0f;

        int lo = min(spa, spb), hi = max(spa, spb);
        int triu = lo * NSPECIES - (lo * (lo - 1)) / 2 + (hi - lo);

        v4f rec;
        rec.x = (d1 + d2) * 0.5f;
        rec.y = 2.0f * fc1 * fc2;
        rec.z = cosang;
        rec.w = sinang;
        t_rec[t] = rec;
        t_dst[t] = (ca << 5) | triu;
    }
}

// ---------------- kB: radial sections, one block per molecule ----------------
__global__ __launch_bounds__(256) void radial_kernel(
        const float* __restrict__ d_ij,
        const int* __restrict__ pair_indices,
        const int* __restrict__ species,
        const int* __restrict__ pstart,
        float* __restrict__ out, int P, int natoms) {
    __shared__ float rows[M_ATOMS * RADLEN];   // 10752 B
    __shared__ v4f stage[MAXPAIR];             // 4416 B

    int tid = threadIdx.x;
    int mol = blockIdx.x;
    int base = mol * M_ATOMS;
    if (base >= natoms) return;

    int p_lo = pstart[mol];
    int p_hi = pstart[mol + 1];
    int np = p_hi - p_lo;

    v4f z = {0.f, 0.f, 0.f, 0.f};
    v4f* r4 = (v4f*)rows;
    for (int c = tid; c < M_ATOMS * RADLEN / 4; c += 256) r4[c] = z;

    // stage per-pair values once (cosf + gathers hoisted out of the x16 loop)
    for (int k = tid; k < np; k += 256) {
        int p = p_lo + k;
        float d = d_ij[p];
        int i = pair_indices[p];
        int j = pair_indices[P + p];
        int si = species[i];
        int sj = species[j];
        float fc = (d <= 0.51f) ? 0.5f * (__cosf(d * (float)(M_PI / 0.51)) + 1.0f) : 0.0f;
        v4f s;
        s.x = d;
        s.y = 0.25f * fc;
        s.z = __int_as_float(((i - base) << 3) | sj);
        s.w = __int_as_float(((j - base) << 3) | si);
        stage[k] = s;
    }
    __syncthreads();

    int n16 = np * NRBF;
    for (int idx = tid; idx < n16; idx += 256) {
        int pp = idx >> 4;
        int k = idx & 15;
        v4f s = stage[pp];
        float shfr = 0.08f + (float)k * 0.026875f;
        float diff = s.x - shfr;
        float rfv = s.y * __expf(-1970.0f * diff * diff);
        int di = __float_as_int(s.z);
        int dj = __float_as_int(s.w);
        atomicAdd(&rows[(di >> 3) * RADLEN + (di & 7) * NRBF + k], rfv);
        atomicAdd(&rows[(dj >> 3) * RADLEN + (dj & 7) * NRBF + k], rfv);
    }
    __syncthreads();

    // write 24 rows x 112 floats (28 v4f each) at ROWLEN stride
    v4f* ov = (v4f*)out;
    for (int c = tid; c < M_ATOMS * (RADLEN / 4); c += 256) {
        int r = c / (RADLEN / 4);
        int e = c % (RADLEN / 4);
        if (base + r < natoms) {
            v4f v = r4[c];
            __builtin_nontemporal_store(v, &ov[(size_t)(base + r) * (ROWLEN / 4) + e]);
        }
    }
}

// ---------------- kC: angular sections, one block per 8 atoms ----------------
__global__ __launch_bounds__(256) void angular_kernel(
        const v4f* __restrict__ t_rec, const int* __restrict__ t_dst,
        const int* __restrict__ tstart,
        float* __restrict__ out, int natoms) {
    __shared__ float rows[APC * ANGLEN];   // 28672 B

    int tid = threadIdx.x;
    int grp = blockIdx.x;
    int base = grp * APC;
    if (base >= natoms) return;

    int t_lo = tstart[grp];
    int t_hi = tstart[grp + 1];

    v4f z = {0.f, 0.f, 0.f, 0.f};
    v4f* r4 = (v4f*)rows;
    for (int c = tid; c < APC * ANGLEN / 4; c += 256) r4[c] = z;
    __syncthreads();

    int n32 = (t_hi - t_lo) * SUBLEN;
    for (int idx = tid; idx < n32; idx += 256) {
        int t = t_lo + (idx >> 5);
        int l = idx & 31;

        v4f rec = t_rec[t];
        int dst = t_dst[t];

        int aa = l >> 2;
        int zz = l & 3;

        float shfa = 0.08f + (float)aa * 0.03375f;
        float dm = rec.x - shfa;
        float f2 = __expf(-800.0f * dm * dm);

        const float c8 = 0.92387953251f;   // cos(pi/8)
        const float s8 = 0.38268343236f;   // sin(pi/8)
        bool midz = (zz == 1) | (zz == 2);
        float cmag = midz ? s8 : c8;
        float smag = midz ? c8 : s8;
        float cz = (zz >= 2) ? -cmag : cmag;

        float bse = 0.5f * (1.0f + rec.z * cz + rec.w * smag);
        float x = bse * bse;  // ^2
        x = x * x;            // ^4
        x = x * x;            // ^8
        x = x * x;            // ^16
        x = x * x;            // ^32

        float term = rec.y * f2 * x;

        int row = (dst >> 5) - base;
        atomicAdd(&rows[row * ANGLEN + (dst & 31) * SUBLEN + l], term);
    }
    __syncthreads();

    // write 8 rows x 896 floats (224 v4f each) at ROWLEN stride, +ANG_OFF
    v4f* ov = (v4f*)out;
    for (int c = tid; c < APC * (ANGLEN / 4); c += 256) {
        int r = c / (ANGLEN / 4);
        int e = c % (ANGLEN / 4);
        if (base + r < natoms) {
            v4f v = r4[c];
            __builtin_nontemporal_store(v, &ov[(size_t)(base + r) * (ROWLEN / 4) + (ANG_OFF / 4) + e]);
        }
    }
}

extern "C" void kernel_launch(void* const* d_in, const int* in_sizes, int n_in,
                              void* d_out, int out_size, void* d_ws, size_t ws_size,
                              hipStream_t stream) {
    const float* d_ij               = (const float*)d_in[0];
    const float* r_ij               = (const float*)d_in[1];
    const int*   pair_indices       = (const int*)d_in[2];
    const int*   species            = (const int*)d_in[3];
    const int*   close_idx          = (const int*)d_in[4];
    const int*   central_atom_index = (const int*)d_in[5];
    const int*   pair_index12       = (const int*)d_in[6];
    const int*   sign12             = (const int*)d_in[7];
    float* out = (float*)d_out;

    int P      = in_sizes[0];
    int T      = in_sizes[5];
    int natoms = in_sizes[3];
    int nmol   = natoms / M_ATOMS;        // 4000
    int ngrp   = (natoms + APC - 1) / APC; // 12000

    // workspace layout (t_rec first for 16B alignment)
    char* w = (char*)d_ws;
    v4f* t_rec  = (v4f*)w;                 w += (size_t)T * 16;
    int* t_dst  = (int*)w;                 w += (size_t)T * 4;
    int* pstart = (int*)w;                 w += (size_t)(nmol + 1) * 4;
    int* tstart = (int*)w;

    int n = max(P, T) + 1;
    setup_kernel<<<(n + 255) / 256, 256, 0, stream>>>(r_ij, pair_indices, species, close_idx,
                                                      central_atom_index, pair_index12, sign12,
                                                      t_rec, t_dst, pstart, tstart,
                                                      P, T, nmol, ngrp);
    radial_kernel<<<nmol, 256, 0, stream>>>(d_ij, pair_indices, species, pstart, out, P, natoms);
    angular_kernel<<<ngrp, 256, 0, stream>>>(t_rec, t_dst, tstart, out, natoms);
}